// Round 6
// baseline (137.014 us; speedup 1.0000x reference)
//
#include <hip/hip_runtime.h>
#include <math.h>

typedef unsigned short u16;
typedef __bf16 bf16x8 __attribute__((ext_vector_type(8)));
typedef float f32x4 __attribute__((ext_vector_type(4)));

// ---------- helpers ----------
__device__ inline u16 bf16_rn(float x) {
    unsigned u = __float_as_uint(x);
    return (u16)((u + 0x7FFFu + ((u >> 16) & 1u)) >> 16);
}
__device__ inline void split2(float x, u16& h, u16& l) {
    h = bf16_rn(x);
    float hf = __uint_as_float(((unsigned)h) << 16);
    l = bf16_rn(x - hf);
}
__device__ inline uint2 pack4(u16 a, u16 b, u16 c, u16 d) {
    uint2 r;
    r.x = (unsigned)a | ((unsigned)b << 16);
    r.y = (unsigned)c | ((unsigned)d << 16);
    return r;
}
__device__ inline f32x4 mfma16(bf16x8 a, bf16x8 b, f32x4 c) {
    return __builtin_amdgcn_mfma_f32_16x16x32_bf16(a, b, c, 0, 0, 0);
}

// ---------- Node A: prep_a (b<1024) + u-partials (1024..1215) + zero (1216..1218) ----------
__global__ __launch_bounds__(256) void k_pre(const float* __restrict__ x,
                                             const float* __restrict__ q,
                                             const float* __restrict__ p,
                                             const float* __restrict__ W1,
                                             u16* __restrict__ Ah, u16* __restrict__ Al,
                                             float* __restrict__ Upart,
                                             float* __restrict__ out,
                                             float* __restrict__ Vacc) {
    int b = blockIdx.x, t = threadIdx.x;
    if (b < 1024) {
        int idx = (b * 256 + t) * 4;  // W1 rows 0..1023 (A block)
        float4 v = *(const float4*)(W1 + idx);
        u16 h0, l0, h1, l1, h2, l2, h3, l3;
        split2(v.x, h0, l0); split2(v.y, h1, l1); split2(v.z, h2, l2); split2(v.w, h3, l3);
        *(uint2*)&Ah[idx] = pack4(h0, h1, h2, h3);
        *(uint2*)&Al[idx] = pack4(l0, l1, l2, l3);
    } else if (b < 1216) {
        int jc = b - 1024;             // 0..191
        int k = (jc & 3) * 256 + t;    // 4 k-groups
        int j0 = (jc >> 2) * 64;       // 48 j-chunks (64-aligned, never straddles x/q/p)
        __shared__ float zs[64];
        if (t < 64) {
            int j = j0 + t;
            zs[t] = (j < 1024) ? x[j] : (j < 2048 ? q[j - 1024] : p[j - 2048]);
        }
        __syncthreads();
        float acc = 0.f;
#pragma unroll 8
        for (int j = 0; j < 64; ++j) acc += zs[j] * W1[(j0 + j) * 1024 + k];
        Upart[(jc >> 2) * 1024 + k] = acc;  // plain store, no atomics
    } else {
        int idx = ((b - 1216) * 256 + t) * 4;  // 3072 floats: out[2048] + Vacc[1024]
        if (idx < 2048) *(float4*)(out + idx) = make_float4(0.f, 0.f, 0.f, 0.f);
        else *(float4*)(Vacc + idx - 2048) = make_float4(0.f, 0.f, 0.f, 0.f);
    }
}

// ---------- Node C: reduce U -> h1/d1 (local), split W2 -> W2h/W2l, transpose+d1-scale
// -> WTh/WTl, Vacc partials; m0==0 blocks publish H1/D1 ----------
__global__ __launch_bounds__(256) void k_w2v(const float* __restrict__ W2,
                                             const float* __restrict__ b1,
                                             const float* __restrict__ Upart,
                                             float* __restrict__ H1g, float* __restrict__ D1g,
                                             u16* __restrict__ W2h, u16* __restrict__ W2l,
                                             u16* __restrict__ WTh, u16* __restrict__ WTl,
                                             float* __restrict__ Vacc) {
    __shared__ float T[64][65];
    __shared__ float hs[64], ds[64];
    int k0 = blockIdx.y * 64, m0 = blockIdx.x * 64;
    int t = threadIdx.x;
    if (t < 64) {
        float u = 0.f;
#pragma unroll 8
        for (int c = 0; c < 48; ++c) u += Upart[c * 1024 + k0 + t];
        float h = tanhf(u + b1[k0 + t]);
        hs[t] = h;
        ds[t] = 1.f - h * h;
        if (m0 == 0) { H1g[k0 + t] = h; D1g[k0 + t] = 1.f - h * h; }
    }
    __syncthreads();
    int rr = t >> 4, cc = (t & 15) * 4;
    float4 vp = make_float4(0.f, 0.f, 0.f, 0.f);
#pragma unroll
    for (int j = 0; j < 4; ++j) {
        int r = rr + j * 16;
        float4 v = *(const float4*)(W2 + (k0 + r) * 1024 + m0 + cc);
        T[r][cc + 0] = v.x; T[r][cc + 1] = v.y; T[r][cc + 2] = v.z; T[r][cc + 3] = v.w;
        u16 h0, l0, h1, l1, h2, l2, h3, l3;
        split2(v.x, h0, l0); split2(v.y, h1, l1); split2(v.z, h2, l2); split2(v.w, h3, l3);
        *(uint2*)&W2h[(k0 + r) * 1024 + m0 + cc] = pack4(h0, h1, h2, h3);
        *(uint2*)&W2l[(k0 + r) * 1024 + m0 + cc] = pack4(l0, l1, l2, l3);
        float hk = hs[r];
        vp.x += hk * v.x; vp.y += hk * v.y; vp.z += hk * v.z; vp.w += hk * v.w;
    }
    vp.x += __shfl_xor(vp.x, 16); vp.y += __shfl_xor(vp.y, 16);
    vp.z += __shfl_xor(vp.z, 16); vp.w += __shfl_xor(vp.w, 16);
    vp.x += __shfl_xor(vp.x, 32); vp.y += __shfl_xor(vp.y, 32);
    vp.z += __shfl_xor(vp.z, 32); vp.w += __shfl_xor(vp.w, 32);
    if (((t & 63) >> 4) == 0) {
        atomicAdd(&Vacc[m0 + cc + 0], vp.x);
        atomicAdd(&Vacc[m0 + cc + 1], vp.y);
        atomicAdd(&Vacc[m0 + cc + 2], vp.z);
        atomicAdd(&Vacc[m0 + cc + 3], vp.w);
    }
    __syncthreads();
#pragma unroll
    for (int j = 0; j < 4; ++j) {
        int mrow = rr + j * 16;
        float f0 = T[cc + 0][mrow] * ds[cc + 0];
        float f1 = T[cc + 1][mrow] * ds[cc + 1];
        float f2 = T[cc + 2][mrow] * ds[cc + 2];
        float f3 = T[cc + 3][mrow] * ds[cc + 3];
        u16 h0, l0, h1, l1, h2, l2, h3, l3;
        split2(f0, h0, l0); split2(f1, h1, l1); split2(f2, h2, l2); split2(f3, h3, l3);
        *(uint2*)&WTh[(m0 + mrow) * 1024 + k0 + cc] = pack4(h0, h1, h2, h3);
        *(uint2*)&WTl[(m0 + mrow) * 1024 + k0 + cc] = pack4(l0, l1, l2, l3);
    }
}

// ---------- Node k_g: Avec[k] = -2 h1 d1 * (W2[k,:] . Svec), Svec built in LDS from Vacc ----------
__global__ __launch_bounds__(256) void k_g(const float* __restrict__ W2,
                                           const float* __restrict__ Vacc,
                                           const float* __restrict__ b2,
                                           const float* __restrict__ W3,
                                           const float* __restrict__ H1,
                                           const float* __restrict__ D1,
                                           float* __restrict__ Avec) {
    __shared__ float sv[1024];
    int k = blockIdx.x;  // grid 1024
    int t = threadIdx.x;
#pragma unroll
    for (int j = 0; j < 4; ++j) {
        int m = t * 4 + j;
        float h = tanhf(Vacc[m] + b2[m]);
        sv[m] = (1.f - h * h) * W3[m];
    }
    __syncthreads();
    float acc = 0.f;
#pragma unroll
    for (int m = t; m < 1024; m += 256) acc += W2[k * 1024 + m] * sv[m];
    for (int o = 32; o; o >>= 1) acc += __shfl_down(acc, o);
    __shared__ float red[4];
    int lane = t & 63, w = t >> 6;
    if (lane == 0) red[w] = acc;
    __syncthreads();
    if (t == 0) Avec[k] = -2.f * H1[k] * D1[k] * (red[0] + red[1] + red[2] + red[3]);
}

// ---------- dbuf BK=64 MFMA GEMMs ----------
// LDK = 66 u16 = 33 dwords (ODD): fragment reads hit banks (tx + 4*qy) mod 32,
// staging writes hit ((tid>>2) + 8*(tid&3)) mod 32 -> all 32 banks used, ~8
// dword-requests/bank (wave64 minimum). LDK=68 (even dwords) used only the 16
// even banks -> 2x LDS serialization on every access.
#define LDK 66
__global__ __launch_bounds__(256) void k_gemm1(const u16* __restrict__ Ah, const u16* __restrict__ Al,
                                               const u16* __restrict__ Bh, const u16* __restrict__ Bl,
                                               const float* __restrict__ Vacc,
                                               const float* __restrict__ b2,
                                               const float* __restrict__ W3,
                                               u16* __restrict__ Sh, u16* __restrict__ Sl) {
    __shared__ u16 As[2][2][64 * LDK];  // [buf][h/l]
    __shared__ u16 Bs[2][2][64 * LDK];
    int tid = threadIdx.x, lane = tid & 63, wv = tid >> 6;
    int wy = wv >> 1, wx = wv & 1;
    int i0 = blockIdx.y * 64, m0 = blockIdx.x * 64;
    int srow = tid >> 2, sseg = (tid & 3) * 16;
    int ldso = srow * LDK + sseg;
    const u16* ap_h = Ah + (i0 + srow) * 1024 + sseg;
    const u16* ap_l = Al + (i0 + srow) * 1024 + sseg;
    const u16* bp_h = Bh + (m0 + srow) * 1024 + sseg;
    const u16* bp_l = Bl + (m0 + srow) * 1024 + sseg;
    int tx = lane & 15, qy = lane >> 4;
    int raA0 = (wy * 32 + tx) * LDK, raA1 = raA0 + 16 * LDK;
    int rbB0 = (wx * 32 + tx) * LDK, rbB1 = rbB0 + 16 * LDK;
    f32x4 acc[2][2];
#pragma unroll
    for (int a = 0; a < 2; ++a)
#pragma unroll
        for (int b = 0; b < 2; ++b) acc[a][b] = (f32x4){0.f, 0.f, 0.f, 0.f};

    // stage k0=0 into buf 0
    *(uint4*)&As[0][0][ldso] = *(const uint4*)(ap_h);
    *(uint4*)&As[0][0][ldso + 8] = *(const uint4*)(ap_h + 8);
    *(uint4*)&As[0][1][ldso] = *(const uint4*)(ap_l);
    *(uint4*)&As[0][1][ldso + 8] = *(const uint4*)(ap_l + 8);
    *(uint4*)&Bs[0][0][ldso] = *(const uint4*)(bp_h);
    *(uint4*)&Bs[0][0][ldso + 8] = *(const uint4*)(bp_h + 8);
    *(uint4*)&Bs[0][1][ldso] = *(const uint4*)(bp_l);
    *(uint4*)&Bs[0][1][ldso + 8] = *(const uint4*)(bp_l + 8);

    for (int k0 = 0; k0 < 1024; k0 += 64) {
        int buf = (k0 >> 6) & 1;
        int kn = (k0 + 64) & 1023;  // last iter wraps (staged but never read)
        uint4 pa0 = *(const uint4*)(ap_h + kn), pa1 = *(const uint4*)(ap_h + kn + 8);
        uint4 pb0 = *(const uint4*)(ap_l + kn), pb1 = *(const uint4*)(ap_l + kn + 8);
        uint4 pc0 = *(const uint4*)(bp_h + kn), pc1 = *(const uint4*)(bp_h + kn + 8);
        uint4 pd0 = *(const uint4*)(bp_l + kn), pd1 = *(const uint4*)(bp_l + kn + 8);
        __syncthreads();
#pragma unroll
        for (int ks = 0; ks < 2; ++ks) {
            int o = ks * 32 + qy * 8;
            bf16x8 aH0 = *(const bf16x8*)&As[buf][0][raA0 + o];
            bf16x8 aH1 = *(const bf16x8*)&As[buf][0][raA1 + o];
            bf16x8 aL0 = *(const bf16x8*)&As[buf][1][raA0 + o];
            bf16x8 aL1 = *(const bf16x8*)&As[buf][1][raA1 + o];
            bf16x8 bH0 = *(const bf16x8*)&Bs[buf][0][rbB0 + o];
            bf16x8 bH1 = *(const bf16x8*)&Bs[buf][0][rbB1 + o];
            bf16x8 bL0 = *(const bf16x8*)&Bs[buf][1][rbB0 + o];
            bf16x8 bL1 = *(const bf16x8*)&Bs[buf][1][rbB1 + o];
            acc[0][0] = mfma16(aH0, bH0, acc[0][0]);
            acc[0][0] = mfma16(aH0, bL0, acc[0][0]);
            acc[0][0] = mfma16(aL0, bH0, acc[0][0]);
            acc[0][1] = mfma16(aH0, bH1, acc[0][1]);
            acc[0][1] = mfma16(aH0, bL1, acc[0][1]);
            acc[0][1] = mfma16(aL0, bH1, acc[0][1]);
            acc[1][0] = mfma16(aH1, bH0, acc[1][0]);
            acc[1][0] = mfma16(aH1, bL0, acc[1][0]);
            acc[1][0] = mfma16(aL1, bH0, acc[1][0]);
            acc[1][1] = mfma16(aH1, bH1, acc[1][1]);
            acc[1][1] = mfma16(aH1, bL1, acc[1][1]);
            acc[1][1] = mfma16(aL1, bH1, acc[1][1]);
        }
        int nb = buf ^ 1;
        *(uint4*)&As[nb][0][ldso] = pa0; *(uint4*)&As[nb][0][ldso + 8] = pa1;
        *(uint4*)&As[nb][1][ldso] = pb0; *(uint4*)&As[nb][1][ldso + 8] = pb1;
        *(uint4*)&Bs[nb][0][ldso] = pc0; *(uint4*)&Bs[nb][0][ldso + 8] = pc1;
        *(uint4*)&Bs[nb][1][ldso] = pd0; *(uint4*)&Bs[nb][1][ldso + 8] = pd1;
    }
#pragma unroll
    for (int sj = 0; sj < 2; ++sj) {
        int m = m0 + wx * 32 + sj * 16 + tx;
        float hv = tanhf(Vacc[m] + b2[m]);
        float d2 = 1.f - hv * hv;
        float cm = -2.f * hv * d2 * W3[m];  // Cvec inline
#pragma unroll
        for (int si = 0; si < 2; ++si) {
            int ib = i0 + wy * 32 + si * 16 + qy * 4;
#pragma unroll
            for (int r = 0; r < 4; ++r) {
                float v = acc[si][sj][r] * cm;
                u16 h, l;
                split2(v, h, l);
                Sh[(ib + r) * 1024 + m] = h;
                Sl[(ib + r) * 1024 + m] = l;
            }
        }
    }
}

__global__ __launch_bounds__(256) void k_gemm2(const u16* __restrict__ Sh, const u16* __restrict__ Sl,
                                               const u16* __restrict__ W2h, const u16* __restrict__ W2l,
                                               const float* __restrict__ W1,
                                               const float* __restrict__ D1,
                                               const float* __restrict__ Avec,
                                               float* __restrict__ out) {
    __shared__ u16 As[2][2][64 * LDK];
    __shared__ u16 Bs[2][2][64 * LDK];
    int tid = threadIdx.x, lane = tid & 63, wv = tid >> 6;
    int wy = wv >> 1, wx = wv & 1;
    int i0 = blockIdx.y * 64, k0g = blockIdx.x * 64;
    int srow = tid >> 2, sseg = (tid & 3) * 16;
    int ldso = srow * LDK + sseg;
    const u16* ap_h = Sh + (i0 + srow) * 1024 + sseg;
    const u16* ap_l = Sl + (i0 + srow) * 1024 + sseg;
    const u16* bp_h = W2h + (k0g + srow) * 1024 + sseg;
    const u16* bp_l = W2l + (k0g + srow) * 1024 + sseg;
    int tx = lane & 15, qy = lane >> 4;
    int raA0 = (wy * 32 + tx) * LDK, raA1 = raA0 + 16 * LDK;
    int rbB0 = (wx * 32 + tx) * LDK, rbB1 = rbB0 + 16 * LDK;
    f32x4 acc[2][2];
#pragma unroll
    for (int a = 0; a < 2; ++a)
#pragma unroll
        for (int b = 0; b < 2; ++b) acc[a][b] = (f32x4){0.f, 0.f, 0.f, 0.f};

    *(uint4*)&As[0][0][ldso] = *(const uint4*)(ap_h);
    *(uint4*)&As[0][0][ldso + 8] = *(const uint4*)(ap_h + 8);
    *(uint4*)&As[0][1][ldso] = *(const uint4*)(ap_l);
    *(uint4*)&As[0][1][ldso + 8] = *(const uint4*)(ap_l + 8);
    *(uint4*)&Bs[0][0][ldso] = *(const uint4*)(bp_h);
    *(uint4*)&Bs[0][0][ldso + 8] = *(const uint4*)(bp_h + 8);
    *(uint4*)&Bs[0][1][ldso] = *(const uint4*)(bp_l);
    *(uint4*)&Bs[0][1][ldso + 8] = *(const uint4*)(bp_l + 8);

    for (int m0 = 0; m0 < 1024; m0 += 64) {
        int buf = (m0 >> 6) & 1;
        int mn = (m0 + 64) & 1023;
        uint4 pa0 = *(const uint4*)(ap_h + mn), pa1 = *(const uint4*)(ap_h + mn + 8);
        uint4 pb0 = *(const uint4*)(ap_l + mn), pb1 = *(const uint4*)(ap_l + mn + 8);
        uint4 pc0 = *(const uint4*)(bp_h + mn), pc1 = *(const uint4*)(bp_h + mn + 8);
        uint4 pd0 = *(const uint4*)(bp_l + mn), pd1 = *(const uint4*)(bp_l + mn + 8);
        __syncthreads();
#pragma unroll
        for (int ks = 0; ks < 2; ++ks) {
            int o = ks * 32 + qy * 8;
            bf16x8 aH0 = *(const bf16x8*)&As[buf][0][raA0 + o];
            bf16x8 aH1 = *(const bf16x8*)&As[buf][0][raA1 + o];
            bf16x8 aL0 = *(const bf16x8*)&As[buf][1][raA0 + o];
            bf16x8 aL1 = *(const bf16x8*)&As[buf][1][raA1 + o];
            bf16x8 bH0 = *(const bf16x8*)&Bs[buf][0][rbB0 + o];
            bf16x8 bH1 = *(const bf16x8*)&Bs[buf][0][rbB1 + o];
            bf16x8 bL0 = *(const bf16x8*)&Bs[buf][1][rbB0 + o];
            bf16x8 bL1 = *(const bf16x8*)&Bs[buf][1][rbB1 + o];
            acc[0][0] = mfma16(aH0, bH0, acc[0][0]);
            acc[0][0] = mfma16(aH0, bL0, acc[0][0]);
            acc[0][0] = mfma16(aL0, bH0, acc[0][0]);
            acc[0][1] = mfma16(aH0, bH1, acc[0][1]);
            acc[0][1] = mfma16(aH0, bL1, acc[0][1]);
            acc[0][1] = mfma16(aL0, bH1, acc[0][1]);
            acc[1][0] = mfma16(aH1, bH0, acc[1][0]);
            acc[1][0] = mfma16(aH1, bL0, acc[1][0]);
            acc[1][0] = mfma16(aL1, bH0, acc[1][0]);
            acc[1][1] = mfma16(aH1, bH1, acc[1][1]);
            acc[1][1] = mfma16(aH1, bL1, acc[1][1]);
            acc[1][1] = mfma16(aL1, bH1, acc[1][1]);
        }
        int nb = buf ^ 1;
        *(uint4*)&As[nb][0][ldso] = pa0; *(uint4*)&As[nb][0][ldso + 8] = pa1;
        *(uint4*)&As[nb][1][ldso] = pb0; *(uint4*)&As[nb][1][ldso + 8] = pb1;
        *(uint4*)&Bs[nb][0][ldso] = pc0; *(uint4*)&Bs[nb][0][ldso + 8] = pc1;
        *(uint4*)&Bs[nb][1][ldso] = pd0; *(uint4*)&Bs[nb][1][ldso + 8] = pd1;
    }
    // fused epilogue: DR = Avec[k]*W1[i,k] + D1[k]*Wm[i,k]; dot with q/p rows of W1
    int kk[2];
    float d1v[2], avv[2];
#pragma unroll
    for (int sj = 0; sj < 2; ++sj) {
        kk[sj] = k0g + wx * 32 + sj * 16 + tx;
        d1v[sj] = D1[kk[sj]];
        avv[sj] = Avec[kk[sj]];
    }
#pragma unroll
    for (int si = 0; si < 2; ++si) {
        int ib = i0 + wy * 32 + si * 16 + qy * 4;
#pragma unroll
        for (int r = 0; r < 4; ++r) {
            int i = ib + r;
            float pq = 0.f, pp = 0.f;
#pragma unroll
            for (int sj = 0; sj < 2; ++sj) {
                int k = kk[sj];
                float dr = avv[sj] * W1[i * 1024 + k] + d1v[sj] * acc[si][sj][r];
                pq += W1[(1024 + i) * 1024 + k] * dr;
                pp += W1[(2048 + i) * 1024 + k] * dr;
            }
            for (int o = 1; o < 16; o <<= 1) {
                pq += __shfl_xor(pq, o);
                pp += __shfl_xor(pp, o);
            }
            if (tx == 0) {
                atomicAdd(&out[i], pp);
                atomicAdd(&out[1024 + i], -pq);
            }
        }
    }
}

extern "C" void kernel_launch(void* const* d_in, const int* in_sizes, int n_in,
                              void* d_out, int out_size, void* d_ws, size_t ws_size,
                              hipStream_t stream) {
    const float* x = (const float*)d_in[0];
    const float* q = (const float*)d_in[1];
    const float* p = (const float*)d_in[2];
    const float* W1 = (const float*)d_in[3];
    const float* b1 = (const float*)d_in[4];
    const float* W2 = (const float*)d_in[5];
    const float* b2 = (const float*)d_in[6];
    const float* W3 = (const float*)d_in[7];
    float* out = (float*)d_out;
    float* ws = (float*)d_ws;
    float* H1 = ws, *D1 = ws + 1024, *Avec = ws + 2048, *Vacc = ws + 3072;
    float* Upart = ws + 4096;  // 48*1024 floats
    u16* u0 = (u16*)(ws + 65536);
    u16* Ah = u0;
    u16* Al = u0 + 1048576;
    u16* WTh = u0 + 2097152;
    u16* WTl = u0 + 3145728;
    u16* W2h = u0 + 4194304;
    u16* W2l = u0 + 5242880;
    u16* Sh = u0 + 6291456;
    u16* Sl = u0 + 7340032;

    k_pre<<<1219, 256, 0, stream>>>(x, q, p, W1, Ah, Al, Upart, out, Vacc);
    k_w2v<<<dim3(16, 16), 256, 0, stream>>>(W2, b1, Upart, H1, D1, W2h, W2l, WTh, WTl, Vacc);
    k_gemm1<<<dim3(16, 16), 256, 0, stream>>>(Ah, Al, WTh, WTl, Vacc, b2, W3, Sh, Sl);
    k_g<<<1024, 256, 0, stream>>>(W2, Vacc, b2, W3, H1, D1, Avec);
    k_gemm2<<<dim3(16, 16), 256, 0, stream>>>(Sh, Sl, W2h, W2l, W1, D1, Avec, out);
}

// Round 7
// 130.231 us; speedup vs baseline: 1.0521x; 1.0521x over previous
//
#include <hip/hip_runtime.h>
#include <math.h>

typedef unsigned short u16;
typedef __bf16 bf16x8 __attribute__((ext_vector_type(8)));
typedef float f32x4 __attribute__((ext_vector_type(4)));

// ---------- helpers ----------
__device__ inline u16 bf16_rn(float x) {
    unsigned u = __float_as_uint(x);
    return (u16)((u + 0x7FFFu + ((u >> 16) & 1u)) >> 16);
}
__device__ inline void split2(float x, u16& h, u16& l) {
    h = bf16_rn(x);
    float hf = __uint_as_float(((unsigned)h) << 16);
    l = bf16_rn(x - hf);
}
__device__ inline uint2 pack4(u16 a, u16 b, u16 c, u16 d) {
    uint2 r;
    r.x = (unsigned)a | ((unsigned)b << 16);
    r.y = (unsigned)c | ((unsigned)d << 16);
    return r;
}
__device__ inline f32x4 mfma16(bf16x8 a, bf16x8 b, f32x4 c) {
    return __builtin_amdgcn_mfma_f32_16x16x32_bf16(a, b, c, 0, 0, 0);
}

// ---------- Node A: prep_a (b<1024) + u-partials (1024..1215) + zero (1216..1218) ----------
__global__ __launch_bounds__(256) void k_pre(const float* __restrict__ x,
                                             const float* __restrict__ q,
                                             const float* __restrict__ p,
                                             const float* __restrict__ W1,
                                             u16* __restrict__ Ah, u16* __restrict__ Al,
                                             float* __restrict__ Upart,
                                             float* __restrict__ out,
                                             float* __restrict__ Vacc) {
    int b = blockIdx.x, t = threadIdx.x;
    if (b < 1024) {
        int idx = (b * 256 + t) * 4;  // W1 rows 0..1023 (A block)
        float4 v = *(const float4*)(W1 + idx);
        u16 h0, l0, h1, l1, h2, l2, h3, l3;
        split2(v.x, h0, l0); split2(v.y, h1, l1); split2(v.z, h2, l2); split2(v.w, h3, l3);
        *(uint2*)&Ah[idx] = pack4(h0, h1, h2, h3);
        *(uint2*)&Al[idx] = pack4(l0, l1, l2, l3);
    } else if (b < 1216) {
        int jc = b - 1024;             // 0..191
        int k = (jc & 3) * 256 + t;    // 4 k-groups
        int j0 = (jc >> 2) * 64;       // 48 j-chunks (64-aligned, never straddles x/q/p)
        __shared__ float zs[64];
        if (t < 64) {
            int j = j0 + t;
            zs[t] = (j < 1024) ? x[j] : (j < 2048 ? q[j - 1024] : p[j - 2048]);
        }
        __syncthreads();
        float acc = 0.f;
#pragma unroll 8
        for (int j = 0; j < 64; ++j) acc += zs[j] * W1[(j0 + j) * 1024 + k];
        Upart[(jc >> 2) * 1024 + k] = acc;  // plain store, no atomics
    } else {
        int idx = ((b - 1216) * 256 + t) * 4;  // 3072 floats: out[2048] + Vacc[1024]
        if (idx < 2048) *(float4*)(out + idx) = make_float4(0.f, 0.f, 0.f, 0.f);
        else *(float4*)(Vacc + idx - 2048) = make_float4(0.f, 0.f, 0.f, 0.f);
    }
}

// ---------- Node C: reduce U -> h1/d1 (local), split W2 -> W2h/W2l, transpose+d1-scale
// -> WTh/WTl, Vacc partials; m0==0 blocks publish H1/D1 ----------
__global__ __launch_bounds__(256) void k_w2v(const float* __restrict__ W2,
                                             const float* __restrict__ b1,
                                             const float* __restrict__ Upart,
                                             float* __restrict__ H1g, float* __restrict__ D1g,
                                             u16* __restrict__ W2h, u16* __restrict__ W2l,
                                             u16* __restrict__ WTh, u16* __restrict__ WTl,
                                             float* __restrict__ Vacc) {
    __shared__ float T[64][65];
    __shared__ float hs[64], ds[64];
    int k0 = blockIdx.y * 64, m0 = blockIdx.x * 64;
    int t = threadIdx.x;
    if (t < 64) {
        float u = 0.f;
#pragma unroll 8
        for (int c = 0; c < 48; ++c) u += Upart[c * 1024 + k0 + t];
        float h = tanhf(u + b1[k0 + t]);
        hs[t] = h;
        ds[t] = 1.f - h * h;
        if (m0 == 0) { H1g[k0 + t] = h; D1g[k0 + t] = 1.f - h * h; }
    }
    __syncthreads();
    int rr = t >> 4, cc = (t & 15) * 4;
    float4 vp = make_float4(0.f, 0.f, 0.f, 0.f);
#pragma unroll
    for (int j = 0; j < 4; ++j) {
        int r = rr + j * 16;
        float4 v = *(const float4*)(W2 + (k0 + r) * 1024 + m0 + cc);
        T[r][cc + 0] = v.x; T[r][cc + 1] = v.y; T[r][cc + 2] = v.z; T[r][cc + 3] = v.w;
        u16 h0, l0, h1, l1, h2, l2, h3, l3;
        split2(v.x, h0, l0); split2(v.y, h1, l1); split2(v.z, h2, l2); split2(v.w, h3, l3);
        *(uint2*)&W2h[(k0 + r) * 1024 + m0 + cc] = pack4(h0, h1, h2, h3);
        *(uint2*)&W2l[(k0 + r) * 1024 + m0 + cc] = pack4(l0, l1, l2, l3);
        float hk = hs[r];
        vp.x += hk * v.x; vp.y += hk * v.y; vp.z += hk * v.z; vp.w += hk * v.w;
    }
    vp.x += __shfl_xor(vp.x, 16); vp.y += __shfl_xor(vp.y, 16);
    vp.z += __shfl_xor(vp.z, 16); vp.w += __shfl_xor(vp.w, 16);
    vp.x += __shfl_xor(vp.x, 32); vp.y += __shfl_xor(vp.y, 32);
    vp.z += __shfl_xor(vp.z, 32); vp.w += __shfl_xor(vp.w, 32);
    if (((t & 63) >> 4) == 0) {
        atomicAdd(&Vacc[m0 + cc + 0], vp.x);
        atomicAdd(&Vacc[m0 + cc + 1], vp.y);
        atomicAdd(&Vacc[m0 + cc + 2], vp.z);
        atomicAdd(&Vacc[m0 + cc + 3], vp.w);
    }
    __syncthreads();
#pragma unroll
    for (int j = 0; j < 4; ++j) {
        int mrow = rr + j * 16;
        float f0 = T[cc + 0][mrow] * ds[cc + 0];
        float f1 = T[cc + 1][mrow] * ds[cc + 1];
        float f2 = T[cc + 2][mrow] * ds[cc + 2];
        float f3 = T[cc + 3][mrow] * ds[cc + 3];
        u16 h0, l0, h1, l1, h2, l2, h3, l3;
        split2(f0, h0, l0); split2(f1, h1, l1); split2(f2, h2, l2); split2(f3, h3, l3);
        *(uint2*)&WTh[(m0 + mrow) * 1024 + k0 + cc] = pack4(h0, h1, h2, h3);
        *(uint2*)&WTl[(m0 + mrow) * 1024 + k0 + cc] = pack4(l0, l1, l2, l3);
    }
}

// ---------- Node k_g: Avec[k] = -2 h1 d1 * (W2[k,:] . Svec), Svec built in LDS from Vacc ----------
__global__ __launch_bounds__(256) void k_g(const float* __restrict__ W2,
                                           const float* __restrict__ Vacc,
                                           const float* __restrict__ b2,
                                           const float* __restrict__ W3,
                                           const float* __restrict__ H1,
                                           const float* __restrict__ D1,
                                           float* __restrict__ Avec) {
    __shared__ float sv[1024];
    int k = blockIdx.x;  // grid 1024
    int t = threadIdx.x;
#pragma unroll
    for (int j = 0; j < 4; ++j) {
        int m = t * 4 + j;
        float h = tanhf(Vacc[m] + b2[m]);
        sv[m] = (1.f - h * h) * W3[m];
    }
    __syncthreads();
    float acc = 0.f;
#pragma unroll
    for (int m = t; m < 1024; m += 256) acc += W2[k * 1024 + m] * sv[m];
    for (int o = 32; o; o >>= 1) acc += __shfl_down(acc, o);
    __shared__ float red[4];
    int lane = t & 63, w = t >> 6;
    if (lane == 0) red[w] = acc;
    __syncthreads();
    if (t == 0) Avec[k] = -2.f * H1[k] * D1[k] * (red[0] + red[1] + red[2] + red[3]);
}

// ---------- dbuf BK=64 MFMA GEMMs, 512 threads = 8 waves = 2 waves/SIMD ----------
// Wave layout 2x4: wave (wy,wx) computes rows [wy*32,+32) x cols [wx*16,+16).
// One 16B global load per thread per matrix per K64 iter; single barrier/iter.
#define LDK 68
__global__ __launch_bounds__(512) void k_gemm1(const u16* __restrict__ Ah, const u16* __restrict__ Al,
                                               const u16* __restrict__ Bh, const u16* __restrict__ Bl,
                                               const float* __restrict__ Vacc,
                                               const float* __restrict__ b2,
                                               const float* __restrict__ W3,
                                               u16* __restrict__ Sh, u16* __restrict__ Sl) {
    __shared__ u16 As[2][2][64 * LDK];  // [buf][h/l]
    __shared__ u16 Bs[2][2][64 * LDK];
    int tid = threadIdx.x, lane = tid & 63, wv = tid >> 6;  // wv 0..7
    int wy = wv >> 2, wx = wv & 3;
    int i0 = blockIdx.y * 64, m0 = blockIdx.x * 64;
    int srow = tid >> 3, sseg = (tid & 7) * 8;
    int ldso = srow * LDK + sseg;
    const u16* ap_h = Ah + (i0 + srow) * 1024 + sseg;
    const u16* ap_l = Al + (i0 + srow) * 1024 + sseg;
    const u16* bp_h = Bh + (m0 + srow) * 1024 + sseg;
    const u16* bp_l = Bl + (m0 + srow) * 1024 + sseg;
    int tx = lane & 15, qy = lane >> 4;
    int raA0 = (wy * 32 + tx) * LDK, raA1 = raA0 + 16 * LDK;
    int rbB0 = (wx * 16 + tx) * LDK;
    f32x4 acc[2];
    acc[0] = (f32x4){0.f, 0.f, 0.f, 0.f};
    acc[1] = (f32x4){0.f, 0.f, 0.f, 0.f};

    // stage k0=0 into buf 0
    *(uint4*)&As[0][0][ldso] = *(const uint4*)(ap_h);
    *(uint4*)&As[0][1][ldso] = *(const uint4*)(ap_l);
    *(uint4*)&Bs[0][0][ldso] = *(const uint4*)(bp_h);
    *(uint4*)&Bs[0][1][ldso] = *(const uint4*)(bp_l);

    for (int k0 = 0; k0 < 1024; k0 += 64) {
        int buf = (k0 >> 6) & 1;
        int kn = (k0 + 64) & 1023;  // last iter wraps (staged but never read)
        uint4 pa = *(const uint4*)(ap_h + kn);
        uint4 pb = *(const uint4*)(ap_l + kn);
        uint4 pc = *(const uint4*)(bp_h + kn);
        uint4 pd = *(const uint4*)(bp_l + kn);
        __syncthreads();
#pragma unroll
        for (int ks = 0; ks < 2; ++ks) {
            int o = ks * 32 + qy * 8;
            bf16x8 aH0 = *(const bf16x8*)&As[buf][0][raA0 + o];
            bf16x8 aH1 = *(const bf16x8*)&As[buf][0][raA1 + o];
            bf16x8 aL0 = *(const bf16x8*)&As[buf][1][raA0 + o];
            bf16x8 aL1 = *(const bf16x8*)&As[buf][1][raA1 + o];
            bf16x8 bH0 = *(const bf16x8*)&Bs[buf][0][rbB0 + o];
            bf16x8 bL0 = *(const bf16x8*)&Bs[buf][1][rbB0 + o];
            acc[0] = mfma16(aH0, bH0, acc[0]);
            acc[0] = mfma16(aH0, bL0, acc[0]);
            acc[0] = mfma16(aL0, bH0, acc[0]);
            acc[1] = mfma16(aH1, bH0, acc[1]);
            acc[1] = mfma16(aH1, bL0, acc[1]);
            acc[1] = mfma16(aL1, bH0, acc[1]);
        }
        int nb = buf ^ 1;
        *(uint4*)&As[nb][0][ldso] = pa;
        *(uint4*)&As[nb][1][ldso] = pb;
        *(uint4*)&Bs[nb][0][ldso] = pc;
        *(uint4*)&Bs[nb][1][ldso] = pd;
    }
    int m = m0 + wx * 16 + tx;
    float hv = tanhf(Vacc[m] + b2[m]);
    float d2 = 1.f - hv * hv;
    float cm = -2.f * hv * d2 * W3[m];  // Cvec inline
#pragma unroll
    for (int si = 0; si < 2; ++si) {
        int ib = i0 + wy * 32 + si * 16 + qy * 4;
#pragma unroll
        for (int r = 0; r < 4; ++r) {
            float v = acc[si][r] * cm;
            u16 h, l;
            split2(v, h, l);
            Sh[(ib + r) * 1024 + m] = h;
            Sl[(ib + r) * 1024 + m] = l;
        }
    }
}

__global__ __launch_bounds__(512) void k_gemm2(const u16* __restrict__ Sh, const u16* __restrict__ Sl,
                                               const u16* __restrict__ W2h, const u16* __restrict__ W2l,
                                               const float* __restrict__ W1,
                                               const float* __restrict__ D1,
                                               const float* __restrict__ Avec,
                                               float* __restrict__ out) {
    __shared__ u16 As[2][2][64 * LDK];
    __shared__ u16 Bs[2][2][64 * LDK];
    int tid = threadIdx.x, lane = tid & 63, wv = tid >> 6;
    int wy = wv >> 2, wx = wv & 3;
    int i0 = blockIdx.y * 64, k0g = blockIdx.x * 64;
    int srow = tid >> 3, sseg = (tid & 7) * 8;
    int ldso = srow * LDK + sseg;
    const u16* ap_h = Sh + (i0 + srow) * 1024 + sseg;
    const u16* ap_l = Sl + (i0 + srow) * 1024 + sseg;
    const u16* bp_h = W2h + (k0g + srow) * 1024 + sseg;
    const u16* bp_l = W2l + (k0g + srow) * 1024 + sseg;
    int tx = lane & 15, qy = lane >> 4;
    int raA0 = (wy * 32 + tx) * LDK, raA1 = raA0 + 16 * LDK;
    int rbB0 = (wx * 16 + tx) * LDK;
    f32x4 acc[2];
    acc[0] = (f32x4){0.f, 0.f, 0.f, 0.f};
    acc[1] = (f32x4){0.f, 0.f, 0.f, 0.f};

    *(uint4*)&As[0][0][ldso] = *(const uint4*)(ap_h);
    *(uint4*)&As[0][1][ldso] = *(const uint4*)(ap_l);
    *(uint4*)&Bs[0][0][ldso] = *(const uint4*)(bp_h);
    *(uint4*)&Bs[0][1][ldso] = *(const uint4*)(bp_l);

    for (int m0 = 0; m0 < 1024; m0 += 64) {
        int buf = (m0 >> 6) & 1;
        int mn = (m0 + 64) & 1023;
        uint4 pa = *(const uint4*)(ap_h + mn);
        uint4 pb = *(const uint4*)(ap_l + mn);
        uint4 pc = *(const uint4*)(bp_h + mn);
        uint4 pd = *(const uint4*)(bp_l + mn);
        __syncthreads();
#pragma unroll
        for (int ks = 0; ks < 2; ++ks) {
            int o = ks * 32 + qy * 8;
            bf16x8 aH0 = *(const bf16x8*)&As[buf][0][raA0 + o];
            bf16x8 aH1 = *(const bf16x8*)&As[buf][0][raA1 + o];
            bf16x8 aL0 = *(const bf16x8*)&As[buf][1][raA0 + o];
            bf16x8 aL1 = *(const bf16x8*)&As[buf][1][raA1 + o];
            bf16x8 bH0 = *(const bf16x8*)&Bs[buf][0][rbB0 + o];
            bf16x8 bL0 = *(const bf16x8*)&Bs[buf][1][rbB0 + o];
            acc[0] = mfma16(aH0, bH0, acc[0]);
            acc[0] = mfma16(aH0, bL0, acc[0]);
            acc[0] = mfma16(aL0, bH0, acc[0]);
            acc[1] = mfma16(aH1, bH0, acc[1]);
            acc[1] = mfma16(aH1, bL0, acc[1]);
            acc[1] = mfma16(aL1, bH0, acc[1]);
        }
        int nb = buf ^ 1;
        *(uint4*)&As[nb][0][ldso] = pa;
        *(uint4*)&As[nb][1][ldso] = pb;
        *(uint4*)&Bs[nb][0][ldso] = pc;
        *(uint4*)&Bs[nb][1][ldso] = pd;
    }
    // fused epilogue: DR = Avec[k]*W1[i,k] + D1[k]*Wm[i,k]; dot with q/p rows of W1
    int kk = k0g + wx * 16 + tx;
    float d1v = D1[kk];
    float avv = Avec[kk];
#pragma unroll
    for (int si = 0; si < 2; ++si) {
        int ib = i0 + wy * 32 + si * 16 + qy * 4;
#pragma unroll
        for (int r = 0; r < 4; ++r) {
            int i = ib + r;
            float dr = avv * W1[i * 1024 + kk] + d1v * acc[si][r];
            float pq = W1[(1024 + i) * 1024 + kk] * dr;
            float pp = W1[(2048 + i) * 1024 + kk] * dr;
            for (int o = 1; o < 16; o <<= 1) {
                pq += __shfl_xor(pq, o);
                pp += __shfl_xor(pp, o);
            }
            if (tx == 0) {
                atomicAdd(&out[i], pp);
                atomicAdd(&out[1024 + i], -pq);
            }
        }
    }
}

extern "C" void kernel_launch(void* const* d_in, const int* in_sizes, int n_in,
                              void* d_out, int out_size, void* d_ws, size_t ws_size,
                              hipStream_t stream) {
    const float* x = (const float*)d_in[0];
    const float* q = (const float*)d_in[1];
    const float* p = (const float*)d_in[2];
    const float* W1 = (const float*)d_in[3];
    const float* b1 = (const float*)d_in[4];
    const float* W2 = (const float*)d_in[5];
    const float* b2 = (const float*)d_in[6];
    const float* W3 = (const float*)d_in[7];
    float* out = (float*)d_out;
    float* ws = (float*)d_ws;
    float* H1 = ws, *D1 = ws + 1024, *Avec = ws + 2048, *Vacc = ws + 3072;
    float* Upart = ws + 4096;  // 48*1024 floats
    u16* u0 = (u16*)(ws + 65536);
    u16* Ah = u0;
    u16* Al = u0 + 1048576;
    u16* WTh = u0 + 2097152;
    u16* WTl = u0 + 3145728;
    u16* W2h = u0 + 4194304;
    u16* W2l = u0 + 5242880;
    u16* Sh = u0 + 6291456;
    u16* Sl = u0 + 7340032;

    k_pre<<<1219, 256, 0, stream>>>(x, q, p, W1, Ah, Al, Upart, out, Vacc);
    k_w2v<<<dim3(16, 16), 256, 0, stream>>>(W2, b1, Upart, H1, D1, W2h, W2l, WTh, WTl, Vacc);
    k_gemm1<<<dim3(16, 16), 512, 0, stream>>>(Ah, Al, WTh, WTl, Vacc, b2, W3, Sh, Sl);
    k_g<<<1024, 256, 0, stream>>>(W2, Vacc, b2, W3, H1, D1, Avec);
    k_gemm2<<<dim3(16, 16), 512, 0, stream>>>(Sh, Sl, W2h, W2l, W1, D1, Avec, out);
}

// Round 8
// 127.781 us; speedup vs baseline: 1.0723x; 1.0192x over previous
//
#include <hip/hip_runtime.h>
#include <math.h>

typedef unsigned short u16;
typedef __bf16 bf16x8 __attribute__((ext_vector_type(8)));
typedef float f32x4 __attribute__((ext_vector_type(4)));

// ---------- helpers ----------
__device__ inline u16 bf16_rn(float x) {
    unsigned u = __float_as_uint(x);
    return (u16)((u + 0x7FFFu + ((u >> 16) & 1u)) >> 16);
}
__device__ inline void split2(float x, u16& h, u16& l) {
    h = bf16_rn(x);
    float hf = __uint_as_float(((unsigned)h) << 16);
    l = bf16_rn(x - hf);
}
__device__ inline uint2 pack4(u16 a, u16 b, u16 c, u16 d) {
    uint2 r;
    r.x = (unsigned)a | ((unsigned)b << 16);
    r.y = (unsigned)c | ((unsigned)d << 16);
    return r;
}
__device__ inline f32x4 mfma16(bf16x8 a, bf16x8 b, f32x4 c) {
    return __builtin_amdgcn_mfma_f32_16x16x32_bf16(a, b, c, 0, 0, 0);
}

// ---------- Node A: prep_a (b<1024) + u-partials (1024..1215) + zero (1216..1218) ----------
__global__ __launch_bounds__(256) void k_pre(const float* __restrict__ x,
                                             const float* __restrict__ q,
                                             const float* __restrict__ p,
                                             const float* __restrict__ W1,
                                             u16* __restrict__ Ah, u16* __restrict__ Al,
                                             float* __restrict__ Upart,
                                             float* __restrict__ out,
                                             float* __restrict__ Vacc) {
    int b = blockIdx.x, t = threadIdx.x;
    if (b < 1024) {
        int idx = (b * 256 + t) * 4;  // W1 rows 0..1023 (A block)
        float4 v = *(const float4*)(W1 + idx);
        u16 h0, l0, h1, l1, h2, l2, h3, l3;
        split2(v.x, h0, l0); split2(v.y, h1, l1); split2(v.z, h2, l2); split2(v.w, h3, l3);
        *(uint2*)&Ah[idx] = pack4(h0, h1, h2, h3);
        *(uint2*)&Al[idx] = pack4(l0, l1, l2, l3);
    } else if (b < 1216) {
        int jc = b - 1024;             // 0..191
        int k = (jc & 3) * 256 + t;    // 4 k-groups
        int j0 = (jc >> 2) * 64;       // 48 j-chunks (64-aligned, never straddles x/q/p)
        __shared__ float zs[64];
        if (t < 64) {
            int j = j0 + t;
            zs[t] = (j < 1024) ? x[j] : (j < 2048 ? q[j - 1024] : p[j - 2048]);
        }
        __syncthreads();
        float acc = 0.f;
#pragma unroll 8
        for (int j = 0; j < 64; ++j) acc += zs[j] * W1[(j0 + j) * 1024 + k];
        Upart[(jc >> 2) * 1024 + k] = acc;  // plain store, no atomics
    } else {
        int idx = ((b - 1216) * 256 + t) * 4;  // 3072 floats: out[2048] + Vacc[1024]
        if (idx < 2048) *(float4*)(out + idx) = make_float4(0.f, 0.f, 0.f, 0.f);
        else *(float4*)(Vacc + idx - 2048) = make_float4(0.f, 0.f, 0.f, 0.f);
    }
}

// ---------- Node C: reduce U -> h1/d1 (local), split W2 -> W2h/W2l, transpose+d1-scale
// -> WTh/WTl, Vacc partials; m0==0 blocks publish H1/D1 ----------
__global__ __launch_bounds__(256) void k_w2v(const float* __restrict__ W2,
                                             const float* __restrict__ b1,
                                             const float* __restrict__ Upart,
                                             float* __restrict__ H1g, float* __restrict__ D1g,
                                             u16* __restrict__ W2h, u16* __restrict__ W2l,
                                             u16* __restrict__ WTh, u16* __restrict__ WTl,
                                             float* __restrict__ Vacc) {
    __shared__ float T[64][65];
    __shared__ float hs[64], ds[64];
    int k0 = blockIdx.y * 64, m0 = blockIdx.x * 64;
    int t = threadIdx.x;
    if (t < 64) {
        float u = 0.f;
#pragma unroll 8
        for (int c = 0; c < 48; ++c) u += Upart[c * 1024 + k0 + t];
        float h = tanhf(u + b1[k0 + t]);
        hs[t] = h;
        ds[t] = 1.f - h * h;
        if (m0 == 0) { H1g[k0 + t] = h; D1g[k0 + t] = 1.f - h * h; }
    }
    __syncthreads();
    int rr = t >> 4, cc = (t & 15) * 4;
    float4 vp = make_float4(0.f, 0.f, 0.f, 0.f);
#pragma unroll
    for (int j = 0; j < 4; ++j) {
        int r = rr + j * 16;
        float4 v = *(const float4*)(W2 + (k0 + r) * 1024 + m0 + cc);
        T[r][cc + 0] = v.x; T[r][cc + 1] = v.y; T[r][cc + 2] = v.z; T[r][cc + 3] = v.w;
        u16 h0, l0, h1, l1, h2, l2, h3, l3;
        split2(v.x, h0, l0); split2(v.y, h1, l1); split2(v.z, h2, l2); split2(v.w, h3, l3);
        *(uint2*)&W2h[(k0 + r) * 1024 + m0 + cc] = pack4(h0, h1, h2, h3);
        *(uint2*)&W2l[(k0 + r) * 1024 + m0 + cc] = pack4(l0, l1, l2, l3);
        float hk = hs[r];
        vp.x += hk * v.x; vp.y += hk * v.y; vp.z += hk * v.z; vp.w += hk * v.w;
    }
    vp.x += __shfl_xor(vp.x, 16); vp.y += __shfl_xor(vp.y, 16);
    vp.z += __shfl_xor(vp.z, 16); vp.w += __shfl_xor(vp.w, 16);
    vp.x += __shfl_xor(vp.x, 32); vp.y += __shfl_xor(vp.y, 32);
    vp.z += __shfl_xor(vp.z, 32); vp.w += __shfl_xor(vp.w, 32);
    if (((t & 63) >> 4) == 0) {
        atomicAdd(&Vacc[m0 + cc + 0], vp.x);
        atomicAdd(&Vacc[m0 + cc + 1], vp.y);
        atomicAdd(&Vacc[m0 + cc + 2], vp.z);
        atomicAdd(&Vacc[m0 + cc + 3], vp.w);
    }
    __syncthreads();
#pragma unroll
    for (int j = 0; j < 4; ++j) {
        int mrow = rr + j * 16;
        float f0 = T[cc + 0][mrow] * ds[cc + 0];
        float f1 = T[cc + 1][mrow] * ds[cc + 1];
        float f2 = T[cc + 2][mrow] * ds[cc + 2];
        float f3 = T[cc + 3][mrow] * ds[cc + 3];
        u16 h0, l0, h1, l1, h2, l2, h3, l3;
        split2(f0, h0, l0); split2(f1, h1, l1); split2(f2, h2, l2); split2(f3, h3, l3);
        *(uint2*)&WTh[(m0 + mrow) * 1024 + k0 + cc] = pack4(h0, h1, h2, h3);
        *(uint2*)&WTl[(m0 + mrow) * 1024 + k0 + cc] = pack4(l0, l1, l2, l3);
    }
}

// ---------- Node k_g: Avec[k] = -2 h1 d1 * (W2[k,:] . Svec), Svec built in LDS from Vacc ----------
__global__ __launch_bounds__(256) void k_g(const float* __restrict__ W2,
                                           const float* __restrict__ Vacc,
                                           const float* __restrict__ b2,
                                           const float* __restrict__ W3,
                                           const float* __restrict__ H1,
                                           const float* __restrict__ D1,
                                           float* __restrict__ Avec) {
    __shared__ float sv[1024];
    int k = blockIdx.x;  // grid 1024
    int t = threadIdx.x;
#pragma unroll
    for (int j = 0; j < 4; ++j) {
        int m = t * 4 + j;
        float h = tanhf(Vacc[m] + b2[m]);
        sv[m] = (1.f - h * h) * W3[m];
    }
    __syncthreads();
    float acc = 0.f;
#pragma unroll
    for (int m = t; m < 1024; m += 256) acc += W2[k * 1024 + m] * sv[m];
    for (int o = 32; o; o >>= 1) acc += __shfl_down(acc, o);
    __shared__ float red[4];
    int lane = t & 63, w = t >> 6;
    if (lane == 0) red[w] = acc;
    __syncthreads();
    if (t == 0) Avec[k] = -2.f * H1[k] * D1[k] * (red[0] + red[1] + red[2] + red[3]);
}

// ---------- dbuf BK=64 MFMA GEMMs, 512 threads = 8 waves = 2 waves/SIMD ----------
// Wave layout: 4 tiles of 32x32 (2x2 over the 64x64 block) x 2 K-halves.
// kh = wv>>2 accumulates K-half kh; partials merged through LDS at the end.
// Minimal wave-tile perimeter -> 64 ds_read_b128/iter (vs 96 in the 2x4
// layout) at unchanged 2 waves/SIMD occupancy.
#define LDK 68
__global__ __launch_bounds__(512) void k_gemm1(const u16* __restrict__ Ah, const u16* __restrict__ Al,
                                               const u16* __restrict__ Bh, const u16* __restrict__ Bl,
                                               const float* __restrict__ Vacc,
                                               const float* __restrict__ b2,
                                               const float* __restrict__ W3,
                                               u16* __restrict__ Sh, u16* __restrict__ Sl) {
    __shared__ u16 As[2][2][64 * LDK];  // [buf][h/l]
    __shared__ u16 Bs[2][2][64 * LDK];
    int tid = threadIdx.x, lane = tid & 63, wv = tid >> 6;  // wv 0..7
    int kh = wv >> 2, wy = (wv >> 1) & 1, wx = wv & 1;
    int i0 = blockIdx.y * 64, m0 = blockIdx.x * 64;
    int srow = tid >> 3, sseg = (tid & 7) * 8;
    int ldso = srow * LDK + sseg;
    const u16* ap_h = Ah + (i0 + srow) * 1024 + sseg;
    const u16* ap_l = Al + (i0 + srow) * 1024 + sseg;
    const u16* bp_h = Bh + (m0 + srow) * 1024 + sseg;
    const u16* bp_l = Bl + (m0 + srow) * 1024 + sseg;
    int tx = lane & 15, qy = lane >> 4;
    int koff = kh * 32 + qy * 8;
    int raA[2], rbB[2];
    raA[0] = (wy * 32 + tx) * LDK + koff;
    raA[1] = raA[0] + 16 * LDK;
    rbB[0] = (wx * 32 + tx) * LDK + koff;
    rbB[1] = rbB[0] + 16 * LDK;
    f32x4 acc[2][2];
#pragma unroll
    for (int a = 0; a < 2; ++a)
#pragma unroll
        for (int b = 0; b < 2; ++b) acc[a][b] = (f32x4){0.f, 0.f, 0.f, 0.f};

    // stage k0=0 into buf 0
    *(uint4*)&As[0][0][ldso] = *(const uint4*)(ap_h);
    *(uint4*)&As[0][1][ldso] = *(const uint4*)(ap_l);
    *(uint4*)&Bs[0][0][ldso] = *(const uint4*)(bp_h);
    *(uint4*)&Bs[0][1][ldso] = *(const uint4*)(bp_l);

    for (int k0 = 0; k0 < 1024; k0 += 64) {
        int buf = (k0 >> 6) & 1;
        int kn = (k0 + 64) & 1023;  // last iter wraps (staged but never read)
        uint4 pa = *(const uint4*)(ap_h + kn);
        uint4 pb = *(const uint4*)(ap_l + kn);
        uint4 pc = *(const uint4*)(bp_h + kn);
        uint4 pd = *(const uint4*)(bp_l + kn);
        __syncthreads();
        bf16x8 aH0 = *(const bf16x8*)&As[buf][0][raA[0]];
        bf16x8 aH1 = *(const bf16x8*)&As[buf][0][raA[1]];
        bf16x8 aL0 = *(const bf16x8*)&As[buf][1][raA[0]];
        bf16x8 aL1 = *(const bf16x8*)&As[buf][1][raA[1]];
        bf16x8 bH0 = *(const bf16x8*)&Bs[buf][0][rbB[0]];
        bf16x8 bH1 = *(const bf16x8*)&Bs[buf][0][rbB[1]];
        bf16x8 bL0 = *(const bf16x8*)&Bs[buf][1][rbB[0]];
        bf16x8 bL1 = *(const bf16x8*)&Bs[buf][1][rbB[1]];
        acc[0][0] = mfma16(aH0, bH0, acc[0][0]);
        acc[0][0] = mfma16(aH0, bL0, acc[0][0]);
        acc[0][0] = mfma16(aL0, bH0, acc[0][0]);
        acc[0][1] = mfma16(aH0, bH1, acc[0][1]);
        acc[0][1] = mfma16(aH0, bL1, acc[0][1]);
        acc[0][1] = mfma16(aL0, bH1, acc[0][1]);
        acc[1][0] = mfma16(aH1, bH0, acc[1][0]);
        acc[1][0] = mfma16(aH1, bL0, acc[1][0]);
        acc[1][0] = mfma16(aL1, bH0, acc[1][0]);
        acc[1][1] = mfma16(aH1, bH1, acc[1][1]);
        acc[1][1] = mfma16(aH1, bL1, acc[1][1]);
        acc[1][1] = mfma16(aL1, bH1, acc[1][1]);
        int nb = buf ^ 1;
        *(uint4*)&As[nb][0][ldso] = pa;
        *(uint4*)&As[nb][1][ldso] = pb;
        *(uint4*)&Bs[nb][0][ldso] = pc;
        *(uint4*)&Bs[nb][1][ldso] = pd;
    }
    // merge K-halves through LDS (reuse As buf as scratch)
    __syncthreads();
    f32x4* mrg = (f32x4*)&As[0][0][0];
    if (kh == 1) {
#pragma unroll
        for (int si = 0; si < 2; ++si)
#pragma unroll
            for (int sj = 0; sj < 2; ++sj)
                mrg[(((wy * 2 + wx) * 4 + si * 2 + sj) * 4 + qy) * 16 + tx] = acc[si][sj];
    }
    __syncthreads();
    if (kh == 0) {
#pragma unroll
        for (int si = 0; si < 2; ++si)
#pragma unroll
            for (int sj = 0; sj < 2; ++sj) {
                f32x4 o = mrg[(((wy * 2 + wx) * 4 + si * 2 + sj) * 4 + qy) * 16 + tx];
                acc[si][sj][0] += o[0]; acc[si][sj][1] += o[1];
                acc[si][sj][2] += o[2]; acc[si][sj][3] += o[3];
            }
#pragma unroll
        for (int sj = 0; sj < 2; ++sj) {
            int m = m0 + wx * 32 + sj * 16 + tx;
            float hv = tanhf(Vacc[m] + b2[m]);
            float d2 = 1.f - hv * hv;
            float cm = -2.f * hv * d2 * W3[m];  // Cvec inline
#pragma unroll
            for (int si = 0; si < 2; ++si) {
                int ib = i0 + wy * 32 + si * 16 + qy * 4;
#pragma unroll
                for (int r = 0; r < 4; ++r) {
                    float v = acc[si][sj][r] * cm;
                    u16 h, l;
                    split2(v, h, l);
                    Sh[(ib + r) * 1024 + m] = h;
                    Sl[(ib + r) * 1024 + m] = l;
                }
            }
        }
    }
}

__global__ __launch_bounds__(512) void k_gemm2(const u16* __restrict__ Sh, const u16* __restrict__ Sl,
                                               const u16* __restrict__ W2h, const u16* __restrict__ W2l,
                                               const float* __restrict__ W1,
                                               const float* __restrict__ D1,
                                               const float* __restrict__ Avec,
                                               float* __restrict__ out) {
    __shared__ u16 As[2][2][64 * LDK];
    __shared__ u16 Bs[2][2][64 * LDK];
    int tid = threadIdx.x, lane = tid & 63, wv = tid >> 6;
    int kh = wv >> 2, wy = (wv >> 1) & 1, wx = wv & 1;
    int i0 = blockIdx.y * 64, k0g = blockIdx.x * 64;
    int srow = tid >> 3, sseg = (tid & 7) * 8;
    int ldso = srow * LDK + sseg;
    const u16* ap_h = Sh + (i0 + srow) * 1024 + sseg;
    const u16* ap_l = Sl + (i0 + srow) * 1024 + sseg;
    const u16* bp_h = W2h + (k0g + srow) * 1024 + sseg;
    const u16* bp_l = W2l + (k0g + srow) * 1024 + sseg;
    int tx = lane & 15, qy = lane >> 4;
    int koff = kh * 32 + qy * 8;
    int raA[2], rbB[2];
    raA[0] = (wy * 32 + tx) * LDK + koff;
    raA[1] = raA[0] + 16 * LDK;
    rbB[0] = (wx * 32 + tx) * LDK + koff;
    rbB[1] = rbB[0] + 16 * LDK;
    f32x4 acc[2][2];
#pragma unroll
    for (int a = 0; a < 2; ++a)
#pragma unroll
        for (int b = 0; b < 2; ++b) acc[a][b] = (f32x4){0.f, 0.f, 0.f, 0.f};

    *(uint4*)&As[0][0][ldso] = *(const uint4*)(ap_h);
    *(uint4*)&As[0][1][ldso] = *(const uint4*)(ap_l);
    *(uint4*)&Bs[0][0][ldso] = *(const uint4*)(bp_h);
    *(uint4*)&Bs[0][1][ldso] = *(const uint4*)(bp_l);

    for (int m0 = 0; m0 < 1024; m0 += 64) {
        int buf = (m0 >> 6) & 1;
        int mn = (m0 + 64) & 1023;
        uint4 pa = *(const uint4*)(ap_h + mn);
        uint4 pb = *(const uint4*)(ap_l + mn);
        uint4 pc = *(const uint4*)(bp_h + mn);
        uint4 pd = *(const uint4*)(bp_l + mn);
        __syncthreads();
        bf16x8 aH0 = *(const bf16x8*)&As[buf][0][raA[0]];
        bf16x8 aH1 = *(const bf16x8*)&As[buf][0][raA[1]];
        bf16x8 aL0 = *(const bf16x8*)&As[buf][1][raA[0]];
        bf16x8 aL1 = *(const bf16x8*)&As[buf][1][raA[1]];
        bf16x8 bH0 = *(const bf16x8*)&Bs[buf][0][rbB[0]];
        bf16x8 bH1 = *(const bf16x8*)&Bs[buf][0][rbB[1]];
        bf16x8 bL0 = *(const bf16x8*)&Bs[buf][1][rbB[0]];
        bf16x8 bL1 = *(const bf16x8*)&Bs[buf][1][rbB[1]];
        acc[0][0] = mfma16(aH0, bH0, acc[0][0]);
        acc[0][0] = mfma16(aH0, bL0, acc[0][0]);
        acc[0][0] = mfma16(aL0, bH0, acc[0][0]);
        acc[0][1] = mfma16(aH0, bH1, acc[0][1]);
        acc[0][1] = mfma16(aH0, bL1, acc[0][1]);
        acc[0][1] = mfma16(aL0, bH1, acc[0][1]);
        acc[1][0] = mfma16(aH1, bH0, acc[1][0]);
        acc[1][0] = mfma16(aH1, bL0, acc[1][0]);
        acc[1][0] = mfma16(aL1, bH0, acc[1][0]);
        acc[1][1] = mfma16(aH1, bH1, acc[1][1]);
        acc[1][1] = mfma16(aH1, bL1, acc[1][1]);
        acc[1][1] = mfma16(aL1, bH1, acc[1][1]);
        int nb = buf ^ 1;
        *(uint4*)&As[nb][0][ldso] = pa;
        *(uint4*)&As[nb][1][ldso] = pb;
        *(uint4*)&Bs[nb][0][ldso] = pc;
        *(uint4*)&Bs[nb][1][ldso] = pd;
    }
    // merge K-halves through LDS
    __syncthreads();
    f32x4* mrg = (f32x4*)&As[0][0][0];
    if (kh == 1) {
#pragma unroll
        for (int si = 0; si < 2; ++si)
#pragma unroll
            for (int sj = 0; sj < 2; ++sj)
                mrg[(((wy * 2 + wx) * 4 + si * 2 + sj) * 4 + qy) * 16 + tx] = acc[si][sj];
    }
    __syncthreads();
    if (kh == 0) {
#pragma unroll
        for (int si = 0; si < 2; ++si)
#pragma unroll
            for (int sj = 0; sj < 2; ++sj) {
                f32x4 o = mrg[(((wy * 2 + wx) * 4 + si * 2 + sj) * 4 + qy) * 16 + tx];
                acc[si][sj][0] += o[0]; acc[si][sj][1] += o[1];
                acc[si][sj][2] += o[2]; acc[si][sj][3] += o[3];
            }
        // fused epilogue: DR = Avec[k]*W1[i,k] + D1[k]*Wm[i,k]; dot with q/p rows of W1
        int kk[2];
        float d1v[2], avv[2];
#pragma unroll
        for (int sj = 0; sj < 2; ++sj) {
            kk[sj] = k0g + wx * 32 + sj * 16 + tx;
            d1v[sj] = D1[kk[sj]];
            avv[sj] = Avec[kk[sj]];
        }
#pragma unroll
        for (int si = 0; si < 2; ++si) {
            int ib = i0 + wy * 32 + si * 16 + qy * 4;
#pragma unroll
            for (int r = 0; r < 4; ++r) {
                int i = ib + r;
                float pq = 0.f, pp = 0.f;
#pragma unroll
                for (int sj = 0; sj < 2; ++sj) {
                    int k = kk[sj];
                    float dr = avv[sj] * W1[i * 1024 + k] + d1v[sj] * acc[si][sj][r];
                    pq += W1[(1024 + i) * 1024 + k] * dr;
                    pp += W1[(2048 + i) * 1024 + k] * dr;
                }
                for (int o = 1; o < 16; o <<= 1) {
                    pq += __shfl_xor(pq, o);
                    pp += __shfl_xor(pp, o);
                }
                if (tx == 0) {
                    atomicAdd(&out[i], pp);
                    atomicAdd(&out[1024 + i], -pq);
                }
            }
        }
    }
}

extern "C" void kernel_launch(void* const* d_in, const int* in_sizes, int n_in,
                              void* d_out, int out_size, void* d_ws, size_t ws_size,
                              hipStream_t stream) {
    const float* x = (const float*)d_in[0];
    const float* q = (const float*)d_in[1];
    const float* p = (const float*)d_in[2];
    const float* W1 = (const float*)d_in[3];
    const float* b1 = (const float*)d_in[4];
    const float* W2 = (const float*)d_in[5];
    const float* b2 = (const float*)d_in[6];
    const float* W3 = (const float*)d_in[7];
    float* out = (float*)d_out;
    float* ws = (float*)d_ws;
    float* H1 = ws, *D1 = ws + 1024, *Avec = ws + 2048, *Vacc = ws + 3072;
    float* Upart = ws + 4096;  // 48*1024 floats
    u16* u0 = (u16*)(ws + 65536);
    u16* Ah = u0;
    u16* Al = u0 + 1048576;
    u16* WTh = u0 + 2097152;
    u16* WTl = u0 + 3145728;
    u16* W2h = u0 + 4194304;
    u16* W2l = u0 + 5242880;
    u16* Sh = u0 + 6291456;
    u16* Sl = u0 + 7340032;

    k_pre<<<1219, 256, 0, stream>>>(x, q, p, W1, Ah, Al, Upart, out, Vacc);
    k_w2v<<<dim3(16, 16), 256, 0, stream>>>(W2, b1, Upart, H1, D1, W2h, W2l, WTh, WTl, Vacc);
    k_gemm1<<<dim3(16, 16), 512, 0, stream>>>(Ah, Al, WTh, WTl, Vacc, b2, W3, Sh, Sl);
    k_g<<<1024, 256, 0, stream>>>(W2, Vacc, b2, W3, H1, D1, Avec);
    k_gemm2<<<dim3(16, 16), 512, 0, stream>>>(Sh, Sl, W2h, W2l, W1, D1, Avec, out);
}

// Round 9
// 119.799 us; speedup vs baseline: 1.1437x; 1.0666x over previous
//
#include <hip/hip_runtime.h>
#include <math.h>

typedef unsigned short u16;
typedef __bf16 bf16x8 __attribute__((ext_vector_type(8)));
typedef float f32x4 __attribute__((ext_vector_type(4)));

// ---------- helpers ----------
__device__ inline u16 bf16_rn(float x) {
    unsigned u = __float_as_uint(x);
    return (u16)((u + 0x7FFFu + ((u >> 16) & 1u)) >> 16);
}
__device__ inline uint2 pack4(u16 a, u16 b, u16 c, u16 d) {
    uint2 r;
    r.x = (unsigned)a | ((unsigned)b << 16);
    r.y = (unsigned)c | ((unsigned)d << 16);
    return r;
}
__device__ inline uint2 pack4f(float a, float b, float c, float d) {
    return pack4(bf16_rn(a), bf16_rn(b), bf16_rn(c), bf16_rn(d));
}
__device__ inline f32x4 mfma16(bf16x8 a, bf16x8 b, f32x4 c) {
    return __builtin_amdgcn_mfma_f32_16x16x32_bf16(a, b, c, 0, 0, 0);
}

// ---------- Node A: prep_a (b<1024) + u-partials (1024..1215) + zero (1216..1218) ----------
__global__ __launch_bounds__(256) void k_pre(const float* __restrict__ x,
                                             const float* __restrict__ q,
                                             const float* __restrict__ p,
                                             const float* __restrict__ W1,
                                             u16* __restrict__ Ah,
                                             float* __restrict__ Upart,
                                             float* __restrict__ out,
                                             float* __restrict__ Vacc) {
    int b = blockIdx.x, t = threadIdx.x;
    if (b < 1024) {
        int idx = (b * 256 + t) * 4;  // W1 rows 0..1023 (A block)
        float4 v = *(const float4*)(W1 + idx);
        *(uint2*)&Ah[idx] = pack4f(v.x, v.y, v.z, v.w);
    } else if (b < 1216) {
        int jc = b - 1024;             // 0..191
        int k = (jc & 3) * 256 + t;    // 4 k-groups
        int j0 = (jc >> 2) * 64;       // 48 j-chunks (64-aligned, never straddles x/q/p)
        __shared__ float zs[64];
        if (t < 64) {
            int j = j0 + t;
            zs[t] = (j < 1024) ? x[j] : (j < 2048 ? q[j - 1024] : p[j - 2048]);
        }
        __syncthreads();
        float acc = 0.f;
#pragma unroll 8
        for (int j = 0; j < 64; ++j) acc += zs[j] * W1[(j0 + j) * 1024 + k];
        Upart[(jc >> 2) * 1024 + k] = acc;  // plain store, no atomics
    } else {
        int idx = ((b - 1216) * 256 + t) * 4;  // 3072 floats: out[2048] + Vacc[1024]
        if (idx < 2048) *(float4*)(out + idx) = make_float4(0.f, 0.f, 0.f, 0.f);
        else *(float4*)(Vacc + idx - 2048) = make_float4(0.f, 0.f, 0.f, 0.f);
    }
}

// ---------- Node C: reduce U -> h1/d1 (local), split W2 -> W2h, transpose+d1-scale
// -> WTh, Vacc partials; m0==0 blocks publish H1/D1 ----------
__global__ __launch_bounds__(256) void k_w2v(const float* __restrict__ W2,
                                             const float* __restrict__ b1,
                                             const float* __restrict__ Upart,
                                             float* __restrict__ H1g, float* __restrict__ D1g,
                                             u16* __restrict__ W2h,
                                             u16* __restrict__ WTh,
                                             float* __restrict__ Vacc) {
    __shared__ float T[64][65];
    __shared__ float hs[64], ds[64];
    int k0 = blockIdx.y * 64, m0 = blockIdx.x * 64;
    int t = threadIdx.x;
    if (t < 64) {
        float u = 0.f;
#pragma unroll 8
        for (int c = 0; c < 48; ++c) u += Upart[c * 1024 + k0 + t];
        float h = tanhf(u + b1[k0 + t]);
        hs[t] = h;
        ds[t] = 1.f - h * h;
        if (m0 == 0) { H1g[k0 + t] = h; D1g[k0 + t] = 1.f - h * h; }
    }
    __syncthreads();
    int rr = t >> 4, cc = (t & 15) * 4;
    float4 vp = make_float4(0.f, 0.f, 0.f, 0.f);
#pragma unroll
    for (int j = 0; j < 4; ++j) {
        int r = rr + j * 16;
        float4 v = *(const float4*)(W2 + (k0 + r) * 1024 + m0 + cc);
        T[r][cc + 0] = v.x; T[r][cc + 1] = v.y; T[r][cc + 2] = v.z; T[r][cc + 3] = v.w;
        *(uint2*)&W2h[(k0 + r) * 1024 + m0 + cc] = pack4f(v.x, v.y, v.z, v.w);
        float hk = hs[r];
        vp.x += hk * v.x; vp.y += hk * v.y; vp.z += hk * v.z; vp.w += hk * v.w;
    }
    vp.x += __shfl_xor(vp.x, 16); vp.y += __shfl_xor(vp.y, 16);
    vp.z += __shfl_xor(vp.z, 16); vp.w += __shfl_xor(vp.w, 16);
    vp.x += __shfl_xor(vp.x, 32); vp.y += __shfl_xor(vp.y, 32);
    vp.z += __shfl_xor(vp.z, 32); vp.w += __shfl_xor(vp.w, 32);
    if (((t & 63) >> 4) == 0) {
        atomicAdd(&Vacc[m0 + cc + 0], vp.x);
        atomicAdd(&Vacc[m0 + cc + 1], vp.y);
        atomicAdd(&Vacc[m0 + cc + 2], vp.z);
        atomicAdd(&Vacc[m0 + cc + 3], vp.w);
    }
    __syncthreads();
#pragma unroll
    for (int j = 0; j < 4; ++j) {
        int mrow = rr + j * 16;
        float f0 = T[cc + 0][mrow] * ds[cc + 0];
        float f1 = T[cc + 1][mrow] * ds[cc + 1];
        float f2 = T[cc + 2][mrow] * ds[cc + 2];
        float f3 = T[cc + 3][mrow] * ds[cc + 3];
        *(uint2*)&WTh[(m0 + mrow) * 1024 + k0 + cc] = pack4f(f0, f1, f2, f3);
    }
}

// ---------- dbuf BK=64 pure-bf16 MFMA GEMMs, 512 threads, split-K waves ----------
// 4 wave-tiles of 32x32 (2x2) x 2 K-halves; merge through LDS at the end.
// Per iter per wave: 4 ds_read_b128 + 4 MFMA. blockIdx.x==16 tail blocks in
// gemm1 compute Avec (the old k_g) -- saves a launch.
#define LDK 68
__global__ __launch_bounds__(512) void k_gemm1(const u16* __restrict__ Ah,
                                               const u16* __restrict__ Bh,
                                               const float* __restrict__ Vacc,
                                               const float* __restrict__ b2,
                                               const float* __restrict__ W3,
                                               const float* __restrict__ W2,
                                               const float* __restrict__ H1,
                                               const float* __restrict__ D1,
                                               float* __restrict__ Avec,
                                               u16* __restrict__ Sh) {
    __shared__ u16 As[2][64 * LDK];
    __shared__ u16 Bs[2][64 * LDK];
    __shared__ float sv[1024];
    int tid = threadIdx.x;
    if (blockIdx.x == 16) {
        // ---- Avec GEMV tail (old k_g), 16 blocks x 64 k ----
        int kbase = blockIdx.y * 64;
#pragma unroll
        for (int j = 0; j < 2; ++j) {
            int m = tid + j * 512;
            float h = tanhf(Vacc[m] + b2[m]);
            sv[m] = (1.f - h * h) * W3[m];
        }
        __syncthreads();
        int g = tid >> 3, sub = tid & 7;
        int k = kbase + g;
        const float* wrow = W2 + k * 1024 + sub * 128;
        const float* svp = sv + sub * 128;
        float acc = 0.f;
#pragma unroll 8
        for (int j = 0; j < 128; ++j) acc += wrow[j] * svp[j];
        acc += __shfl_xor(acc, 1);
        acc += __shfl_xor(acc, 2);
        acc += __shfl_xor(acc, 4);
        if (sub == 0) Avec[k] = -2.f * H1[k] * D1[k] * acc;
        return;
    }
    int lane = tid & 63, wv = tid >> 6;  // wv 0..7
    int kh = wv >> 2, wy = (wv >> 1) & 1, wx = wv & 1;
    int i0 = blockIdx.y * 64, m0 = blockIdx.x * 64;
    int srow = tid >> 3, sseg = (tid & 7) * 8;
    int ldso = srow * LDK + sseg;
    const u16* ap = Ah + (i0 + srow) * 1024 + sseg;
    const u16* bp = Bh + (m0 + srow) * 1024 + sseg;
    int tx = lane & 15, qy = lane >> 4;
    int koff = kh * 32 + qy * 8;
    int raA[2], rbB[2];
    raA[0] = (wy * 32 + tx) * LDK + koff;
    raA[1] = raA[0] + 16 * LDK;
    rbB[0] = (wx * 32 + tx) * LDK + koff;
    rbB[1] = rbB[0] + 16 * LDK;
    f32x4 acc[2][2];
#pragma unroll
    for (int a = 0; a < 2; ++a)
#pragma unroll
        for (int b = 0; b < 2; ++b) acc[a][b] = (f32x4){0.f, 0.f, 0.f, 0.f};

    *(uint4*)&As[0][ldso] = *(const uint4*)(ap);
    *(uint4*)&Bs[0][ldso] = *(const uint4*)(bp);

    for (int k0 = 0; k0 < 1024; k0 += 64) {
        int buf = (k0 >> 6) & 1;
        int kn = (k0 + 64) & 1023;  // last iter wraps (staged but never read)
        uint4 pa = *(const uint4*)(ap + kn);
        uint4 pc = *(const uint4*)(bp + kn);
        __syncthreads();
        bf16x8 aH0 = *(const bf16x8*)&As[buf][raA[0]];
        bf16x8 aH1 = *(const bf16x8*)&As[buf][raA[1]];
        bf16x8 bH0 = *(const bf16x8*)&Bs[buf][rbB[0]];
        bf16x8 bH1 = *(const bf16x8*)&Bs[buf][rbB[1]];
        acc[0][0] = mfma16(aH0, bH0, acc[0][0]);
        acc[0][1] = mfma16(aH0, bH1, acc[0][1]);
        acc[1][0] = mfma16(aH1, bH0, acc[1][0]);
        acc[1][1] = mfma16(aH1, bH1, acc[1][1]);
        int nb = buf ^ 1;
        *(uint4*)&As[nb][ldso] = pa;
        *(uint4*)&Bs[nb][ldso] = pc;
    }
    // merge K-halves through LDS (reuse As as scratch)
    __syncthreads();
    f32x4* mrg = (f32x4*)&As[0][0];
    if (kh == 1) {
#pragma unroll
        for (int si = 0; si < 2; ++si)
#pragma unroll
            for (int sj = 0; sj < 2; ++sj)
                mrg[(((wy * 2 + wx) * 4 + si * 2 + sj) * 4 + qy) * 16 + tx] = acc[si][sj];
    }
    __syncthreads();
    if (kh == 0) {
#pragma unroll
        for (int si = 0; si < 2; ++si)
#pragma unroll
            for (int sj = 0; sj < 2; ++sj) {
                f32x4 o = mrg[(((wy * 2 + wx) * 4 + si * 2 + sj) * 4 + qy) * 16 + tx];
                acc[si][sj][0] += o[0]; acc[si][sj][1] += o[1];
                acc[si][sj][2] += o[2]; acc[si][sj][3] += o[3];
            }
#pragma unroll
        for (int sj = 0; sj < 2; ++sj) {
            int m = m0 + wx * 32 + sj * 16 + tx;
            float hv = tanhf(Vacc[m] + b2[m]);
            float d2 = 1.f - hv * hv;
            float cm = -2.f * hv * d2 * W3[m];  // Cvec inline
#pragma unroll
            for (int si = 0; si < 2; ++si) {
                int ib = i0 + wy * 32 + si * 16 + qy * 4;
#pragma unroll
                for (int r = 0; r < 4; ++r)
                    Sh[(ib + r) * 1024 + m] = bf16_rn(acc[si][sj][r] * cm);
            }
        }
    }
}

__global__ __launch_bounds__(512) void k_gemm2(const u16* __restrict__ Sh,
                                               const u16* __restrict__ W2h,
                                               const float* __restrict__ W1,
                                               const float* __restrict__ D1,
                                               const float* __restrict__ Avec,
                                               float* __restrict__ out) {
    __shared__ u16 As[2][64 * LDK];
    __shared__ u16 Bs[2][64 * LDK];
    int tid = threadIdx.x, lane = tid & 63, wv = tid >> 6;
    int kh = wv >> 2, wy = (wv >> 1) & 1, wx = wv & 1;
    int i0 = blockIdx.y * 64, k0g = blockIdx.x * 64;
    int srow = tid >> 3, sseg = (tid & 7) * 8;
    int ldso = srow * LDK + sseg;
    const u16* ap = Sh + (i0 + srow) * 1024 + sseg;
    const u16* bp = W2h + (k0g + srow) * 1024 + sseg;
    int tx = lane & 15, qy = lane >> 4;
    int koff = kh * 32 + qy * 8;
    int raA[2], rbB[2];
    raA[0] = (wy * 32 + tx) * LDK + koff;
    raA[1] = raA[0] + 16 * LDK;
    rbB[0] = (wx * 32 + tx) * LDK + koff;
    rbB[1] = rbB[0] + 16 * LDK;
    f32x4 acc[2][2];
#pragma unroll
    for (int a = 0; a < 2; ++a)
#pragma unroll
        for (int b = 0; b < 2; ++b) acc[a][b] = (f32x4){0.f, 0.f, 0.f, 0.f};

    *(uint4*)&As[0][ldso] = *(const uint4*)(ap);
    *(uint4*)&Bs[0][ldso] = *(const uint4*)(bp);

    for (int m0 = 0; m0 < 1024; m0 += 64) {
        int buf = (m0 >> 6) & 1;
        int mn = (m0 + 64) & 1023;
        uint4 pa = *(const uint4*)(ap + mn);
        uint4 pc = *(const uint4*)(bp + mn);
        __syncthreads();
        bf16x8 aH0 = *(const bf16x8*)&As[buf][raA[0]];
        bf16x8 aH1 = *(const bf16x8*)&As[buf][raA[1]];
        bf16x8 bH0 = *(const bf16x8*)&Bs[buf][rbB[0]];
        bf16x8 bH1 = *(const bf16x8*)&Bs[buf][rbB[1]];
        acc[0][0] = mfma16(aH0, bH0, acc[0][0]);
        acc[0][1] = mfma16(aH0, bH1, acc[0][1]);
        acc[1][0] = mfma16(aH1, bH0, acc[1][0]);
        acc[1][1] = mfma16(aH1, bH1, acc[1][1]);
        int nb = buf ^ 1;
        *(uint4*)&As[nb][ldso] = pa;
        *(uint4*)&Bs[nb][ldso] = pc;
    }
    // merge K-halves through LDS
    __syncthreads();
    f32x4* mrg = (f32x4*)&As[0][0];
    if (kh == 1) {
#pragma unroll
        for (int si = 0; si < 2; ++si)
#pragma unroll
            for (int sj = 0; sj < 2; ++sj)
                mrg[(((wy * 2 + wx) * 4 + si * 2 + sj) * 4 + qy) * 16 + tx] = acc[si][sj];
    }
    __syncthreads();
    if (kh == 0) {
#pragma unroll
        for (int si = 0; si < 2; ++si)
#pragma unroll
            for (int sj = 0; sj < 2; ++sj) {
                f32x4 o = mrg[(((wy * 2 + wx) * 4 + si * 2 + sj) * 4 + qy) * 16 + tx];
                acc[si][sj][0] += o[0]; acc[si][sj][1] += o[1];
                acc[si][sj][2] += o[2]; acc[si][sj][3] += o[3];
            }
        // fused epilogue: DR = Avec[k]*W1[i,k] + D1[k]*Wm[i,k]; dot with q/p rows of W1
        int kk[2];
        float d1v[2], avv[2];
#pragma unroll
        for (int sj = 0; sj < 2; ++sj) {
            kk[sj] = k0g + wx * 32 + sj * 16 + tx;
            d1v[sj] = D1[kk[sj]];
            avv[sj] = Avec[kk[sj]];
        }
#pragma unroll
        for (int si = 0; si < 2; ++si) {
            int ib = i0 + wy * 32 + si * 16 + qy * 4;
#pragma unroll
            for (int r = 0; r < 4; ++r) {
                int i = ib + r;
                float pq = 0.f, pp = 0.f;
#pragma unroll
                for (int sj = 0; sj < 2; ++sj) {
                    int k = kk[sj];
                    float dr = avv[sj] * W1[i * 1024 + k] + d1v[sj] * acc[si][sj][r];
                    pq += W1[(1024 + i) * 1024 + k] * dr;
                    pp += W1[(2048 + i) * 1024 + k] * dr;
                }
                for (int o = 1; o < 16; o <<= 1) {
                    pq += __shfl_xor(pq, o);
                    pp += __shfl_xor(pp, o);
                }
                if (tx == 0) {
                    atomicAdd(&out[i], pp);
                    atomicAdd(&out[1024 + i], -pq);
                }
            }
        }
    }
}

extern "C" void kernel_launch(void* const* d_in, const int* in_sizes, int n_in,
                              void* d_out, int out_size, void* d_ws, size_t ws_size,
                              hipStream_t stream) {
    const float* x = (const float*)d_in[0];
    const float* q = (const float*)d_in[1];
    const float* p = (const float*)d_in[2];
    const float* W1 = (const float*)d_in[3];
    const float* b1 = (const float*)d_in[4];
    const float* W2 = (const float*)d_in[5];
    const float* b2 = (const float*)d_in[6];
    const float* W3 = (const float*)d_in[7];
    float* out = (float*)d_out;
    float* ws = (float*)d_ws;
    float* H1 = ws, *D1 = ws + 1024, *Avec = ws + 2048, *Vacc = ws + 3072;
    float* Upart = ws + 4096;  // 48*1024 floats
    u16* u0 = (u16*)(ws + 65536);
    u16* Ah = u0;
    u16* WTh = u0 + 1048576;
    u16* W2h = u0 + 2097152;
    u16* Sh = u0 + 3145728;

    k_pre<<<1219, 256, 0, stream>>>(x, q, p, W1, Ah, Upart, out, Vacc);
    k_w2v<<<dim3(16, 16), 256, 0, stream>>>(W2, b1, Upart, H1, D1, W2h, WTh, Vacc);
    k_gemm1<<<dim3(17, 16), 512, 0, stream>>>(Ah, WTh, Vacc, b2, W3, W2, H1, D1, Avec, Sh);
    k_gemm2<<<dim3(16, 16), 512, 0, stream>>>(Sh, W2h, W1, D1, Avec, out);
}